// Round 4
// baseline (1311.038 us; speedup 1.0000x reference)
//
#include <hip/hip_runtime.h>
#include <math.h>

#define BSZ 64
#define TLEN 256
#define LSND 65536
#define ZK 160            // z K-length in bf16 slots: 129 real + iv-residual@129 + pads

typedef __attribute__((ext_vector_type(8))) short bf16x8;
typedef __attribute__((ext_vector_type(4))) float f32x4;

__device__ __forceinline__ float sigm(float x) { return 1.f / (1.f + __expf(-x)); }
__device__ __forceinline__ float tanh_f(float x) {
  float e = __expf(-2.f * fabsf(x));
  return copysignf((1.f - e) / (1.f + e), x);
}
__device__ __forceinline__ unsigned short f2bf(float x) {   // RNE f32->bf16
  unsigned u = __float_as_uint(x);
  return (unsigned short)((u + 0x7FFFu + ((u >> 16) & 1u)) >> 16);
}

union U16x8 { ulonglong2 u2; bf16x8 v; };

// K1: fold linear into w_ih: Wc[n][j] (1024x132, cols>=129 zero); bc = folded bias
__global__ __launch_bounds__(256) void prep_kernel(
    const float* __restrict__ w_ih, const float* __restrict__ lin_w,
    const float* __restrict__ lin_b, const float* __restrict__ b_ih,
    const float* __restrict__ b_hh, float* __restrict__ Wc, float* __restrict__ bc)
{
  __shared__ float sRow[256];
  const int n = blockIdx.x;
  const int j = threadIdx.x;
  sRow[j] = w_ih[n * 256 + j];
  __syncthreads();
  if (j < 132) {
    float acc = 0.f;
    if (j < 129) {
      for (int k = 0; k < 256; ++k) acc += sRow[k] * lin_w[k * 129 + j];
    }
    Wc[n * 132 + j] = acc;
  } else if (j == 255) {
    float acc = b_ih[n] + b_hh[n];
    for (int k = 0; k < 256; ++k) acc += sRow[k] * lin_b[k];
    bc[n] = acc;
  }
}

__global__ __launch_bounds__(256) void transpose_w3(const float* __restrict__ w3,
                                                    float* __restrict__ w3t)
{
  int i = blockIdx.x * 256 + threadIdx.x;
  if (i < 96 * 128) { int s = i >> 7, o = i & 127; w3t[i] = w3[o * 96 + s]; }
}

// K2: gather + conv1/conv2/conv3 -> zw[t][b][ZK] bf16.
// feature 0 = bf16(interval); feature 129 = bf16(interval - bf16(interval)) (hi/lo split,
// both use folded-weight column 0); features 1..128 = y3; 130..159 zero pad.
__global__ __launch_bounds__(64) void conv_kernel(
    const int* __restrict__ alpha, const float* __restrict__ sound,
    const float* __restrict__ w1, const float* __restrict__ b1v,
    const float* __restrict__ w2, const float* __restrict__ b2,
    const float* __restrict__ w3t, const float* __restrict__ b3,
    unsigned short* __restrict__ zw)
{
  __shared__ float win[2048];
  __shared__ float sY2[96];
  const int l = threadIdx.x;
  const int b = blockIdx.x >> 8;
  const int t = blockIdx.x & 255;
  const int a = alpha[b * TLEN + t];
  const int a0 = a - 1024;
  const float* srow = sound + (size_t)b * LSND;
  for (int x = l; x < 2048; x += 64) {
    int p = a0 + x;
    win[x] = (p >= 0 && p < LSND) ? srow[p] : 0.f;
  }
  __syncthreads();
  float acc0 = 0.f, acc1 = 0.f, acc2 = 0.f;
  for (int f = l; f < 2046; f += 64) {
    float wv = w1[f];
    acc0 += win[f] * wv;
    acc1 += win[f + 1] * wv;
    acc2 += win[f + 2] * wv;
  }
  for (int m = 32; m; m >>= 1) {
    acc0 += __shfl_xor(acc0, m);
    acc1 += __shfl_xor(acc1, m);
    acc2 += __shfl_xor(acc2, m);
  }
  const float bb = b1v[0];
  const float y11 = acc0 + bb, y12 = acc1 + bb, y13 = acc2 + bb;
  {
    int s = l;
    int c = s / 3, lp = s - c * 3;
    float wA = w2[c * 3], wB = w2[c * 3 + 1], wC = w2[c * 3 + 2];
    float v = (lp == 0) ? (y11 * wB + y12 * wC)
            : (lp == 1) ? (y11 * wA + y12 * wB + y13 * wC)
                        : (y12 * wA + y13 * wB);
    sY2[s] = fmaxf(v + b2[c], 0.f);
    if (l < 32) {
      s = 64 + l; c = s / 3; lp = s - c * 3;
      wA = w2[c * 3]; wB = w2[c * 3 + 1]; wC = w2[c * 3 + 2];
      v = (lp == 0) ? (y11 * wB + y12 * wC)
        : (lp == 1) ? (y11 * wA + y12 * wB + y13 * wC)
                    : (y12 * wA + y13 * wB);
      sY2[s] = fmaxf(v + b2[c], 0.f);
    }
  }
  __syncthreads();
  float o0 = b3[l], o1 = b3[l + 64];
  for (int s = 0; s < 96; ++s) {
    float yv = sY2[s];
    o0 += yv * w3t[s * 128 + l];
    o1 += yv * w3t[s * 128 + l + 64];
  }
  unsigned short* zrow = zw + ((size_t)t * BSZ + b) * ZK;
  zrow[1 + l] = f2bf(o0);
  zrow[65 + l] = f2bf(o1);
  if (l == 0) {
    int prev = (t > 0) ? alpha[b * TLEN + t - 1] : 0;
    float iv = (float)(a - prev);
    unsigned short hi = f2bf(iv);
    zrow[0] = hi;
    float rec = __uint_as_float(((unsigned)hi) << 16);
    zrow[129] = f2bf(iv - rec);
  }
  if (l < 30) zrow[130 + l] = 0;
}

// K3: MFMA LSTM. 64 blocks (16 jt x 4 bt) x 256 threads; wave = one gate,
// one 16x16x(K=416) bf16 MFMA tile (13 ops). Weights in A-frag VGPRs (static).
// h exchanged through L3 via bypass atomics, published in B-frag memory order
// (bf16, [buf%3][b][j]); per-producer tag written after vmcnt(0). Consumers
// poll 16 tags then load B-frags straight to registers. z-side folded into K
// (k 256..415), prefetched to registers a step ahead (cached loads). Gate
// combine via parity-buffered sD in LDS -> one __syncthreads per step.
__global__ void __launch_bounds__(256, 1) lstm_kernel(
    const unsigned short* __restrict__ zw, const float* __restrict__ Wc,
    const float* __restrict__ bc, const float* __restrict__ w_hh,
    unsigned short* __restrict__ hpub, unsigned int* __restrict__ tags,
    float* __restrict__ hfin)
{
  __shared__ float sD[2][4][320];     // [parity][gate][lane*5 + r]

  const int tid = threadIdx.x;
  const int wv = tid >> 6;            // gate 0..3 (i,f,g,o)
  const int ln = tid & 63;
  const int jt = (int)blockIdx.x >> 2;  // 0..15
  const int bt = (int)blockIdx.x & 3;   // 0..3
  const int bl = ln & 15;             // A-row / B-col lane index
  const int kg = ln >> 4;             // k-group 0..3
  const int b = (bt << 4) + bl;

  // ---- A fragments (weights, loaded once; k-pack order matches B) ----
  bf16x8 afr[13];
  {
    const int row = (wv << 8) + (jt << 4) + bl;   // global gate row
    #pragma unroll
    for (int o = 0; o < 13; ++o) {
      #pragma unroll
      for (int e = 0; e < 8; ++e) {
        int k = o * 32 + kg * 8 + e;
        float w;
        if (k < 256) w = w_hh[row * 256 + k];
        else {
          int kz = k - 256;
          w = (kz < 129) ? Wc[row * 132 + kz] : (kz == 129 ? Wc[row * 132] : 0.f);
        }
        afr[o][e] = (short)f2bf(w);
      }
    }
  }
  float bias[4];
  #pragma unroll
  for (int r = 0; r < 4; ++r)
    bias[r] = bc[(wv << 8) + (jt << 4) + (kg << 2) + r];

  const unsigned long long* hp64 = (const unsigned long long*)hpub;
  unsigned* hp32 = (unsigned*)hpub;

  // ---- z fragment double buffer: zA holds t, zB holds t+1 ----
  ulonglong2 zA[5], zB[5];
  #pragma unroll
  for (int oz = 0; oz < 5; ++oz) {
    zA[oz] = *(const ulonglong2*)(zw + (((size_t)0 * BSZ + b) * ZK + oz * 32 + kg * 8));
    zB[oz] = *(const ulonglong2*)(zw + (((size_t)1 * BSZ + b) * ZK + oz * 32 + kg * 8));
  }
  float c0 = 0.f, c1 = 0.f, c2 = 0.f, c3 = 0.f;

#define STEP(T, SDP, BUF, NBUF, ZC)                                             \
  {                                                                             \
    const int t_ = (T);                                                         \
    f32x4 acc; acc[0] = bias[0]; acc[1] = bias[1]; acc[2] = bias[2]; acc[3] = bias[3]; \
    _Pragma("unroll")                                                           \
    for (int oz = 0; oz < 5; ++oz) {                                            \
      U16x8 u; u.u2 = ZC[oz];                                                   \
      acc = __builtin_amdgcn_mfma_f32_16x16x32_bf16(afr[8 + oz], u.v, acc, 0, 0, 0); \
    }                                                                           \
    if (ln < 16) {                                                              \
      const unsigned* tp = tags + (BUF) * 64 + (bt << 4) + ln;                  \
      unsigned v;                                                               \
      do { v = __hip_atomic_load(tp, __ATOMIC_RELAXED, __HIP_MEMORY_SCOPE_AGENT); } \
      while (v != (unsigned)t_);                                                \
    }                                                                           \
    _Pragma("unroll")                                                           \
    for (int o = 0; o < 8; ++o) {                                               \
      const unsigned long long* hp = hp64 + (size_t)(BUF) * 4096 + b * 64 + o * 8 + kg * 2; \
      U16x8 u;                                                                  \
      u.u2.x = __hip_atomic_load(hp,     __ATOMIC_RELAXED, __HIP_MEMORY_SCOPE_AGENT); \
      u.u2.y = __hip_atomic_load(hp + 1, __ATOMIC_RELAXED, __HIP_MEMORY_SCOPE_AGENT); \
      acc = __builtin_amdgcn_mfma_f32_16x16x32_bf16(afr[o], u.v, acc, 0, 0, 0); \
    }                                                                           \
    sD[SDP][wv][ln * 5 + 0] = acc[0];                                           \
    sD[SDP][wv][ln * 5 + 1] = acc[1];                                           \
    sD[SDP][wv][ln * 5 + 2] = acc[2];                                           \
    sD[SDP][wv][ln * 5 + 3] = acc[3];                                           \
    __syncthreads();                                                            \
    if (wv == 0) {                                                              \
      float hv0, hv1, hv2, hv3;                                                 \
      {                                                                         \
        float gi = sD[SDP][0][ln * 5 + 0], gf = sD[SDP][1][ln * 5 + 0];         \
        float gg = sD[SDP][2][ln * 5 + 0], go = sD[SDP][3][ln * 5 + 0];         \
        c0 = sigm(gf) * c0 + sigm(gi) * tanh_f(gg); hv0 = sigm(go) * tanh_f(c0); \
      }                                                                         \
      {                                                                         \
        float gi = sD[SDP][0][ln * 5 + 1], gf = sD[SDP][1][ln * 5 + 1];         \
        float gg = sD[SDP][2][ln * 5 + 1], go = sD[SDP][3][ln * 5 + 1];         \
        c1 = sigm(gf) * c1 + sigm(gi) * tanh_f(gg); hv1 = sigm(go) * tanh_f(c1); \
      }                                                                         \
      {                                                                         \
        float gi = sD[SDP][0][ln * 5 + 2], gf = sD[SDP][1][ln * 5 + 2];         \
        float gg = sD[SDP][2][ln * 5 + 2], go = sD[SDP][3][ln * 5 + 2];         \
        c2 = sigm(gf) * c2 + sigm(gi) * tanh_f(gg); hv2 = sigm(go) * tanh_f(c2); \
      }                                                                         \
      {                                                                         \
        float gi = sD[SDP][0][ln * 5 + 3], gf = sD[SDP][1][ln * 5 + 3];         \
        float gg = sD[SDP][2][ln * 5 + 3], go = sD[SDP][3][ln * 5 + 3];         \
        c3 = sigm(gf) * c3 + sigm(gi) * tanh_f(gg); hv3 = sigm(go) * tanh_f(c3); \
      }                                                                         \
      unsigned p0 = (unsigned)f2bf(hv0) | ((unsigned)f2bf(hv1) << 16);          \
      unsigned p1 = (unsigned)f2bf(hv2) | ((unsigned)f2bf(hv3) << 16);          \
      unsigned* hq = hp32 + (size_t)(NBUF) * 8192 + b * 128 + (jt << 3) + (kg << 1); \
      __hip_atomic_store(hq,     p0, __ATOMIC_RELAXED, __HIP_MEMORY_SCOPE_AGENT); \
      __hip_atomic_store(hq + 1, p1, __ATOMIC_RELAXED, __HIP_MEMORY_SCOPE_AGENT); \
      if (t_ == TLEN - 1) {                                                     \
        const int j0 = (jt << 4) + (kg << 2);                                   \
        hfin[b * 256 + j0 + 0] = hv0;                                           \
        hfin[b * 256 + j0 + 1] = hv1;                                           \
        hfin[b * 256 + j0 + 2] = hv2;                                           \
        hfin[b * 256 + j0 + 3] = hv3;                                           \
      }                                                                         \
      asm volatile("s_waitcnt vmcnt(0)" ::: "memory");                          \
      if (ln == 0)                                                              \
        __hip_atomic_store(tags + (NBUF) * 64 + (bt << 4) + jt,                 \
                           (unsigned)(t_ + 1), __ATOMIC_RELAXED,                \
                           __HIP_MEMORY_SCOPE_AGENT);                           \
    }                                                                           \
    if (t_ + 2 < TLEN) {                                                        \
      _Pragma("unroll")                                                         \
      for (int oz = 0; oz < 5; ++oz)                                            \
        ZC[oz] = *(const ulonglong2*)(zw + (((size_t)(t_ + 2) * BSZ + b) * ZK + oz * 32 + kg * 8)); \
    }                                                                           \
  }

  int buf = 0;
  #pragma unroll 1
  for (int t = 0; t < TLEN; t += 2) {
    int n1 = buf + 1; if (n1 == 3) n1 = 0;
    int n2 = n1 + 1; if (n2 == 3) n2 = 0;
    STEP(t,     0, buf, n1, zA)
    STEP(t + 1, 1, n1,  n2, zB)
    buf = n2;
  }
#undef STEP
}

// K4: head
__global__ __launch_bounds__(256) void head_kernel(
    const float* __restrict__ hfin, const float* __restrict__ o1w,
    const float* __restrict__ o1b, const float* __restrict__ o2w,
    const float* __restrict__ o2b, float* __restrict__ out)
{
  __shared__ float sR[32];
  const int b = blockIdx.x;
  const int tid = threadIdx.x;
  const int m = tid >> 3, g = tid & 7;
  const float* h = hfin + b * 256;
  float acc = 0.f;
  for (int k = g * 32; k < g * 32 + 32; ++k) acc += h[k] * o1w[m * 256 + k];
  acc += __shfl_xor(acc, 1); acc += __shfl_xor(acc, 2); acc += __shfl_xor(acc, 4);
  if (g == 0) sR[m] = fmaxf(acc + o1b[m], 0.f);
  __syncthreads();
  if (tid == 0) {
    float s = o2b[0];
    for (int mm = 0; mm < 32; ++mm) s += sR[mm] * o2w[mm];
    out[b] = sigm(s);
  }
}

extern "C" void kernel_launch(void* const* d_in, const int* in_sizes, int n_in,
                              void* d_out, int out_size, void* d_ws, size_t ws_size,
                              hipStream_t stream) {
  (void)in_sizes; (void)n_in; (void)out_size; (void)ws_size;
  const int*   alpha = (const int*)  d_in[0];
  const float* sound = (const float*)d_in[1];
  const float* w1    = (const float*)d_in[2];
  const float* b1    = (const float*)d_in[3];
  const float* w2    = (const float*)d_in[4];
  const float* b2    = (const float*)d_in[5];
  const float* w3    = (const float*)d_in[6];
  const float* b3    = (const float*)d_in[7];
  const float* linw  = (const float*)d_in[8];
  const float* linb  = (const float*)d_in[9];
  const float* wih   = (const float*)d_in[10];
  const float* whh   = (const float*)d_in[11];
  const float* bih   = (const float*)d_in[12];
  const float* bhh   = (const float*)d_in[13];
  const float* o1w   = (const float*)d_in[14];
  const float* o1b   = (const float*)d_in[15];
  const float* o2w   = (const float*)d_in[16];
  const float* o2b   = (const float*)d_in[17];

  // byte layout (all offsets 16B-aligned)
  char* p = (char*)d_ws;
  unsigned short* zw   = (unsigned short*)p;               // 256*64*160 u16 = 5,242,880 B
  float*          Wc   = (float*)(p + 5242880);            // 1024*132 f     =   540,672 B
  float*          bc   = (float*)(p + 5783552);            // 1024 f         =     4,096 B
  float*          w3t  = (float*)(p + 5787648);            // 96*128 f       =    49,152 B
  float*          hfin = (float*)(p + 5836800);            // 64*256 f       =    65,536 B
  unsigned short* hpub = (unsigned short*)(p + 5902336);   // 3*64*256 u16   =    98,304 B
  unsigned int*   tags = (unsigned int*)(p + 6000640);     // 3*64 u32       =       768 B

  hipMemsetAsync(p + 5902336, 0, 98304 + 768, stream);     // hpub+tags: tag0 / h0=0

  prep_kernel<<<1024, 256, 0, stream>>>(wih, linw, linb, bih, bhh, Wc, bc);
  transpose_w3<<<48, 256, 0, stream>>>(w3, w3t);
  conv_kernel<<<BSZ * TLEN, 64, 0, stream>>>(alpha, sound, w1, b1, w2, b2, w3t, b3, zw);
  lstm_kernel<<<64, 256, 0, stream>>>(zw, Wc, bc, whh, hpub, tags, hfin);
  head_kernel<<<BSZ, 256, 0, stream>>>(hfin, o1w, o1b, o2w, o2b, (float*)d_out);
}